// Round 6
// baseline (773.440 us; speedup 1.0000x reference)
//
#include <hip/hip_runtime.h>
#include <hip/hip_bf16.h>
#include <math.h>

// ---------------------------------------------------------------------------
// Net: x(B,3,28,28) -> _cor (ch2 correlated with its 11x11 center) -> B,1,28,28
//      conv1 5x5 VALID (32) + relu + maxpool2 -> B,32,12,12   [MFMA fp16]
//      conv2 5x5 VALID (64) + relu + maxpool2 -> B,64,4,4     [MFMA fp16]
//      conv3 3x3 VALID (10) + relu + mean(hw) + log_softmax -> B,10
// pool1 stored fp16 [img][144 pos][32 ic]; rounding point identical to before.
// ---------------------------------------------------------------------------

#define B_STRIDE 2352   // 3*28*28

typedef _Float16 f16x8 __attribute__((ext_vector_type(8)));
typedef _Float16 f16x4 __attribute__((ext_vector_type(4)));
typedef _Float16 f16x2 __attribute__((ext_vector_type(2)));
typedef float f32x4 __attribute__((ext_vector_type(4)));

// ============================ Kernel 1 =====================================
// fused cor + conv1(MFMA) + relu + maxpool2. 512 thr = 8 waves; 1 img/wave,
// 2 rounds. Wave-local phases only (no block barriers after weight stage).
#define K1_WAVES 8
#define K1_ROUNDS 2
__global__ __launch_bounds__(512, 4) void k1_cor_conv1_pool(
    const float* __restrict__ x, const float* __restrict__ w1,
    const float* __restrict__ b1, _Float16* __restrict__ out1h)
{
    __shared__ float PAD[K1_WAVES][1444];        // 38x38 zero-padded ch (f32)
    __shared__ _Float16 COR[K1_WAVES][784];      // 28x28 cor output (f16)
    __shared__ _Float16 AW1[2 * 64 * 8];         // conv1 A-frags, 2 oc-tiles
    __shared__ float b1s[32];

    const int tid = threadIdx.x;
    const int wave = tid >> 6;
    const int lane = tid & 63;

    // ---- stage conv1 A-frags: A[oc][k=tap], taps 25..31 zeroed ----
    for (int e = tid; e < 1024; e += 512) {
        const int ln = (e >> 3) & 63;
        const int oc = ((e >> 9) << 4) + (ln & 15);
        const int k = ((ln >> 4) << 3) + (e & 7);
        AW1[e] = (k < 25) ? (_Float16)w1[oc * 25 + k] : (_Float16)0.f;
    }
    if (tid < 32) b1s[tid] = b1[tid];
    __syncthreads();

    const int g = lane >> 4;        // MFMA k-group / oc-subrow
    const int c = lane & 15;        // MFMA column
    int off[8];
#pragma unroll
    for (int jj = 0; jj < 8; ++jj) {
        const int k = g * 8 + jj;
        const int ky = k / 5;
        off[jj] = (k < 25) ? (ky * 28 + (k - ky * 5)) : 0;
    }
    const f16x8 af0 = *(const f16x8*)&AW1[lane * 8];
    const f16x8 af1 = *(const f16x8*)&AW1[(64 + lane) * 8];
    float bia0[4], bia1[4];
#pragma unroll
    for (int rr = 0; rr < 4; ++rr) {
        bia0[rr] = b1s[g * 4 + rr];
        bia1[rr] = b1s[16 + g * 4 + rr];
    }
    const int yy = lane >> 1;       // cor row (valid < 28)
    const int x0 = (lane & 1) * 14; // cor col base
    float* padw = &PAD[wave][0];
    _Float16* corw = &COR[wave][0];

    for (int r = 0; r < K1_ROUNDS; ++r) {
        const int img = blockIdx.x * (K1_WAVES * K1_ROUNDS) + r * K1_WAVES + wave;

        // ---- zero pad buffer, then fill interior with ch2 ----
        for (int i = lane; i < 361; i += 64)
            ((f32x4*)padw)[i] = (f32x4){0.f, 0.f, 0.f, 0.f};
        const float* xb = x + (size_t)img * B_STRIDE + 1568;  // channel 2
        for (int i = lane; i < 196; i += 64) {
            const float4 v = ((const float4*)xb)[i];
            const int yv = i / 7;
            float* d = &padw[(5 + yv) * 38 + 5 + (i - yv * 7) * 4];
            d[0] = v.x; d[1] = v.y; d[2] = v.z; d[3] = v.w;
        }

        // ---- cor: 56 lanes, one 14-wide half-row each; write f16 ----
        if (yy < 28) {
            float a[14];
#pragma unroll
            for (int t = 0; t < 14; ++t) a[t] = 0.f;
#pragma unroll
            for (int ky = 0; ky < 11; ++ky) {
                const float* prow = &padw[(yy + ky) * 38 + x0];
                float rr2[24];
#pragma unroll
                for (int t2 = 0; t2 < 12; ++t2) {
                    const float2 v2 = ((const float2*)prow)[t2];
                    rr2[2 * t2] = v2.x; rr2[2 * t2 + 1] = v2.y;
                }
                const float* trow = &padw[(13 + ky) * 38 + 13];
#pragma unroll
                for (int kx = 0; kx < 11; ++kx) {
                    const float w = trow[kx];   // broadcast
#pragma unroll
                    for (int t = 0; t < 14; ++t)
                        a[t] = fmaf(rr2[kx + t], w, a[t]);
                }
            }
            _Float16* cw = &corw[yy * 28 + x0];
#pragma unroll
            for (int t2 = 0; t2 < 7; ++t2) {
                f16x2 v2 = {(_Float16)a[2 * t2], (_Float16)a[2 * t2 + 1]};
                *(f16x2*)&cw[2 * t2] = v2;
            }
        }

        // ---- conv1 via MFMA: N ordered q-major so pool is in-lane ----
        _Float16* outw = out1h + (size_t)img * 4608;
#pragma unroll
        for (int jq = 0; jq < 9; ++jq) {
            const int pp = jq * 16 + c;
            const int py = pp / 12, px = pp - py * 12;
            f32x4 pm0, pm1;
#pragma unroll
            for (int q = 0; q < 4; ++q) {
                const int base = (2 * py + (q >> 1)) * 28 + 2 * px + (q & 1);
                f16x8 bf;
#pragma unroll
                for (int jj = 0; jj < 8; ++jj)
                    bf[jj] = corw[base + off[jj]];
                const f32x4 z = {0.f, 0.f, 0.f, 0.f};
                const f32x4 d0 = __builtin_amdgcn_mfma_f32_16x16x32_f16(af0, bf, z, 0, 0, 0);
                const f32x4 d1 = __builtin_amdgcn_mfma_f32_16x16x32_f16(af1, bf, z, 0, 0, 0);
                if (q == 0) { pm0 = d0; pm1 = d1; }
                else {
#pragma unroll
                    for (int rr = 0; rr < 4; ++rr) {
                        pm0[rr] = fmaxf(pm0[rr], d0[rr]);
                        pm1[rr] = fmaxf(pm1[rr], d1[rr]);
                    }
                }
            }
            f16x4 s0, s1;
#pragma unroll
            for (int rr = 0; rr < 4; ++rr) {
                s0[rr] = (_Float16)fmaxf(pm0[rr] + bia0[rr], 0.f);
                s1[rr] = (_Float16)fmaxf(pm1[rr] + bia1[rr], 0.f);
            }
            _Float16* dsth = outw + pp * 32 + g * 4;
            *(f16x4*)dsth = s0;
            *(f16x4*)(dsth + 16) = s1;
        }
    }
}

// ============================ Kernel 2 (MFMA fp16) =========================
// conv2 5x5 VALID (32->64) + relu + maxpool2. 512 thr = 8 waves; each wave
// owns one image per round (4 rounds). XT is an 8-row ring buffer per wave
// (rows mod 8): phase1 stages rows 0..7, computes j=0,1; phase2 stages rows
// 8..11 over slots 0..3, computes j=2,3. No block barriers in the loop;
// next image prefetched into registers during compute (T14).
#define K2_ROUNDS 4
__global__ __launch_bounds__(512, 2) void k2_conv2_pool_mfma(
    const _Float16* __restrict__ in1h, const float* __restrict__ w2,
    const float* __restrict__ b2, float* __restrict__ out2)
{
    __shared__ __align__(16) _Float16 AW[25 * 4 * 64 * 8];   // 100 KB frag-linear
    __shared__ __align__(16) _Float16 XT[8][4 * 96 * 8];     // 8 x 6144 B ring
    __shared__ float b2s[64];

    const int tid = threadIdx.x;
    const int wave = tid >> 6;
    const int lane = tid & 63;

    // ---- stage weights once per block ----
    for (int it = 0; it < 50; ++it) {
        const int flat = it * 512 + tid;             // (oc*16+icp)*25 + kpos
        const int rest = (flat * 5243) >> 17;        // flat / 25
        const int kpos = flat - rest * 25;
        const int oc = rest >> 4, icp = rest & 15;
        const float* gsrc = w2 + oc * 800 + icp * 50 + kpos;
        const f16x2 v = { (_Float16)gsrc[0], (_Float16)gsrc[25] };
        const int lane_w = (oc & 15) + (icp >> 2) * 16;
        const int idx = (((kpos * 4 + (oc >> 4)) * 64) + lane_w) * 8 + (icp & 3) * 2;
        *(f16x2*)&AW[idx] = v;
    }
    if (tid < 64) b2s[tid] = b2[tid];

    const int b0 = blockIdx.x * (8 * K2_ROUNDS);
    const int hi = (lane >> 3) & 1;
    const int ox = lane & 7;
    const int icg = lane >> 4;
    _Float16* xtw = &XT[wave][0];

    // ---- prefetch round-0 image into registers ----
    f16x8 ld1[6], ld2[3];
    {
        const _Float16* src = in1h + (size_t)(b0 + wave) * 4608;
#pragma unroll
        for (int cc = 0; cc < 6; ++cc)
            ld1[cc] = *(const f16x8*)(src + lane * 48 + cc * 8);
#pragma unroll
        for (int cc = 0; cc < 3; ++cc)
            ld2[cc] = *(const f16x8*)(src + 3072 + lane * 24 + cc * 8);
    }
    __syncthreads();   // AW + b2s visible; the only block barrier

    for (int r = 0; r < K2_ROUNDS; ++r) {
        const int img = b0 + r * 8 + wave;

        // ---- phase-1 LDS writes: rows 0..7 ([icg][row&7][col] * 16B) ----
#pragma unroll
        for (int cc = 0; cc < 6; ++cc) {
            const int gb = lane * 96 + cc * 16;
            const int pos = gb >> 6;
            const int r12 = (pos * 2731) >> 15;
            const int col = pos - r12 * 12;
            *(f16x8*)&xtw[((((gb >> 4) & 3) * 96) + (r12 & 7) * 12 + col) * 8] = ld1[cc];
        }

        f32x4 acc[4][4];
#pragma unroll
        for (int i = 0; i < 4; ++i)
#pragma unroll
            for (int j = 0; j < 4; ++j)
                acc[i][j] = (f32x4){0.f, 0.f, 0.f, 0.f};

        // ---- phase-1 compute: j = 0,1 (rows 0..7) ----
#pragma unroll
        for (int kpos = 0; kpos < 25; ++kpos) {
            const int ky = kpos / 5, kx = kpos - (kpos / 5) * 5;
            f16x8 af[4];
#pragma unroll
            for (int i = 0; i < 4; ++i)
                af[i] = *(const f16x8*)&AW[(((kpos * 4 + i) * 64) + lane) * 8];
            const f16x8 bf0 = *(const f16x8*)&xtw[(icg * 96 + ((hi + 0 + ky) & 7) * 12 + ox + kx) * 8];
            const f16x8 bf1 = *(const f16x8*)&xtw[(icg * 96 + ((hi + 2 + ky) & 7) * 12 + ox + kx) * 8];
#pragma unroll
            for (int i = 0; i < 4; ++i) {
                acc[i][0] = __builtin_amdgcn_mfma_f32_16x16x32_f16(af[i], bf0, acc[i][0], 0, 0, 0);
                acc[i][1] = __builtin_amdgcn_mfma_f32_16x16x32_f16(af[i], bf1, acc[i][1], 0, 0, 0);
            }
        }

        // ---- phase-2 LDS writes: rows 8..11 into slots 0..3 ----
#pragma unroll
        for (int cc = 0; cc < 3; ++cc) {
            const int gb = 6144 + lane * 48 + cc * 16;
            const int pos = gb >> 6;
            const int r12 = (pos * 2731) >> 15;
            const int col = pos - r12 * 12;
            *(f16x8*)&xtw[((((gb >> 4) & 3) * 96) + (r12 & 7) * 12 + col) * 8] = ld2[cc];
        }

        // ---- prefetch next round's image (overlaps phase-2 compute) ----
        {
            const int img_pf = b0 + ((r + 1) & (K2_ROUNDS - 1)) * 8 + wave;
            const _Float16* src = in1h + (size_t)img_pf * 4608;
#pragma unroll
            for (int cc = 0; cc < 6; ++cc)
                ld1[cc] = *(const f16x8*)(src + lane * 48 + cc * 8);
#pragma unroll
            for (int cc = 0; cc < 3; ++cc)
                ld2[cc] = *(const f16x8*)(src + 3072 + lane * 24 + cc * 8);
        }

        // ---- phase-2 compute: j = 2,3 (rows 4..11) ----
#pragma unroll
        for (int kpos = 0; kpos < 25; ++kpos) {
            const int ky = kpos / 5, kx = kpos - (kpos / 5) * 5;
            f16x8 af[4];
#pragma unroll
            for (int i = 0; i < 4; ++i)
                af[i] = *(const f16x8*)&AW[(((kpos * 4 + i) * 64) + lane) * 8];
            const f16x8 bf2 = *(const f16x8*)&xtw[(icg * 96 + ((hi + 4 + ky) & 7) * 12 + ox + kx) * 8];
            const f16x8 bf3 = *(const f16x8*)&xtw[(icg * 96 + ((hi + 6 + ky) & 7) * 12 + ox + kx) * 8];
#pragma unroll
            for (int i = 0; i < 4; ++i) {
                acc[i][2] = __builtin_amdgcn_mfma_f32_16x16x32_f16(af[i], bf2, acc[i][2], 0, 0, 0);
                acc[i][3] = __builtin_amdgcn_mfma_f32_16x16x32_f16(af[i], bf3, acc[i][3], 0, 0, 0);
            }
        }

        // ---- epilogue: bias + relu + 2x2 pool + write [64][4][4] ----
        float* dst = out2 + (size_t)img * 1024;
#pragma unroll
        for (int i = 0; i < 4; ++i)
#pragma unroll
            for (int j = 0; j < 4; ++j)
#pragma unroll
                for (int rr = 0; rr < 4; ++rr) {
                    const int oc = i * 16 + (lane >> 4) * 4 + rr;
                    float v = fmaxf(acc[i][j][rr] + b2s[oc], 0.f);
                    v = fmaxf(v, __shfl_xor(v, 1));
                    v = fmaxf(v, __shfl_xor(v, 8));
                    if ((lane & 9) == 0)
                        dst[oc * 16 + j * 4 + (ox >> 1)] = v;
                }
    }
}

// ============================ Kernel 3 =====================================
// conv3 3x3 VALID (64->10) + relu + mean + log_softmax. 512 thr = 8 waves;
// wave owns 1 image/round, 4 rounds; weights staged once; all-lane mapping
// (icq 0..15 x pos 0..3), shuffle-tree reduce, in-lane softmax. No loop barriers.
#define K3_ROUNDS 4
__global__ __launch_bounds__(512, 4) void k3_conv3_head(
    const float* __restrict__ in2, const float* __restrict__ w3,
    const float* __restrict__ b3, float* __restrict__ out)
{
    __shared__ float w3s[5760];            // [oc][ic][3][3] flat
    __shared__ float b3s[16];
    __shared__ float xin[8][64 * 17];      // per-wave, 17-stride channels

    const int tid = threadIdx.x;
    const int wave = tid >> 6;
    const int lane = tid & 63;

    for (int i = tid; i < 5760; i += 512) w3s[i] = w3[i];
    if (tid < 10) b3s[tid] = b3[tid];
    __syncthreads();

    const int icq = lane >> 2;      // 0..15: ic quad
    const int pos = lane & 3;
    const int oy = pos >> 1, oxx = pos & 1;
    float* xw = &xin[wave][0];

    for (int r = 0; r < K3_ROUNDS; ++r) {
        const int img = blockIdx.x * (8 * K3_ROUNDS) + r * 8 + wave;

        // ---- wave-local stage: lane stages channel `lane` (stride 17) ----
        {
            const float4* s4 = (const float4*)(in2 + (size_t)img * 1024 + lane * 16);
            const float4 v0 = s4[0], v1 = s4[1], v2 = s4[2], v3 = s4[3];
            float* d = &xw[lane * 17];
            d[0] = v0.x;  d[1] = v0.y;  d[2] = v0.z;  d[3] = v0.w;
            d[4] = v1.x;  d[5] = v1.y;  d[6] = v1.z;  d[7] = v1.w;
            d[8] = v2.x;  d[9] = v2.y;  d[10] = v2.z; d[11] = v2.w;
            d[12] = v3.x; d[13] = v3.y; d[14] = v3.z; d[15] = v3.w;
        }

        // ---- conv3: lane accumulates 4 ics x 10 ocs over its 3x3 window ----
        float xv[4][9];
#pragma unroll
        for (int il = 0; il < 4; ++il) {
            const float* xc = &xw[(icq * 4 + il) * 17 + oy * 4 + oxx];
#pragma unroll
            for (int ky = 0; ky < 3; ++ky)
#pragma unroll
                for (int kx = 0; kx < 3; ++kx)
                    xv[il][ky * 3 + kx] = xc[ky * 4 + kx];
        }
        float acc[10];
#pragma unroll
        for (int oc = 0; oc < 10; ++oc) {
            float a = 0.f;
#pragma unroll
            for (int il = 0; il < 4; ++il) {
                const float* wc = &w3s[oc * 576 + (icq * 4 + il) * 9];
#pragma unroll
                for (int t = 0; t < 9; ++t)
                    a = fmaf(xv[il][t], wc[t], a);
            }
            acc[oc] = a;
        }

        // ---- reduce over icq (xor 4,8,16,32), bias+relu, mean over pos ----
        float lv[10];
#pragma unroll
        for (int oc = 0; oc < 10; ++oc) {
            float v = acc[oc];
            v += __shfl_xor(v, 4);
            v += __shfl_xor(v, 8);
            v += __shfl_xor(v, 16);
            v += __shfl_xor(v, 32);
            v = fmaxf(v + b3s[oc], 0.f);
            v += __shfl_xor(v, 1);
            v += __shfl_xor(v, 2);
            lv[oc] = v * 0.25f;
        }

        // ---- in-lane log_softmax; lane 0 writes ----
        float mx = lv[0];
#pragma unroll
        for (int oc = 1; oc < 10; ++oc) mx = fmaxf(mx, lv[oc]);
        float s = 0.f;
#pragma unroll
        for (int oc = 0; oc < 10; ++oc) s += expf(lv[oc] - mx);
        const float lse = mx + logf(s);
        if (lane == 0) {
            float* o = out + (size_t)img * 10;
#pragma unroll
            for (int oc = 0; oc < 10; ++oc) o[oc] = lv[oc] - lse;
        }
    }
}

// ============================ Launch =======================================
extern "C" void kernel_launch(void* const* d_in, const int* in_sizes, int n_in,
                              void* d_out, int out_size, void* d_ws, size_t ws_size,
                              hipStream_t stream)
{
    const float* x  = (const float*)d_in[0];
    const float* w1 = (const float*)d_in[1];
    const float* b1 = (const float*)d_in[2];
    const float* w2 = (const float*)d_in[3];
    const float* b2 = (const float*)d_in[4];
    const float* w3 = (const float*)d_in[5];
    const float* b3 = (const float*)d_in[6];
    float* out = (float*)d_out;

    const int B = in_sizes[0] / B_STRIDE;                         // 8192
    _Float16* pool1h = (_Float16*)d_ws;                           // B*4608 f16
    float* pool2 = (float*)((char*)d_ws + (size_t)B * 4608 * 2);  // B*1024 f32

    k1_cor_conv1_pool<<<B / (K1_WAVES * K1_ROUNDS), 512, 0, stream>>>(x, w1, b1, pool1h);
    k2_conv2_pool_mfma<<<B / (8 * K2_ROUNDS), 512, 0, stream>>>(pool1h, w2, b2, pool2);
    k3_conv3_head<<<B / (8 * K3_ROUNDS), 512, 0, stream>>>(pool2, w3, b3, out);
}

// Round 8
// 379.418 us; speedup vs baseline: 2.0385x; 2.0385x over previous
//
#include <hip/hip_runtime.h>
#include <hip/hip_bf16.h>
#include <math.h>

// ---------------------------------------------------------------------------
// Net: x(B,3,28,28) -> _cor (ch2 correlated with its 11x11 center) -> B,1,28,28
//      conv1 5x5 VALID (32) + relu + maxpool2 -> B,32,12,12   [MFMA fp16]
//      conv2 5x5 VALID (64) + relu + maxpool2 -> B,64,4,4     [MFMA fp16]
//      conv3 3x3 VALID (10) + relu + mean(hw) + log_softmax -> B,10
// pool1 stored fp16 [img][144 pos][32 ic].
// k2 = exact Round-3 structure (proven 90 us, ideal FETCH/WRITE).
// ---------------------------------------------------------------------------

#define B_STRIDE 2352   // 3*28*28

typedef _Float16 f16x8 __attribute__((ext_vector_type(8)));
typedef _Float16 f16x4 __attribute__((ext_vector_type(4)));
typedef _Float16 f16x2 __attribute__((ext_vector_type(2)));
typedef float f32x4 __attribute__((ext_vector_type(4)));

// ============================ Kernel 1 =====================================
// fused cor + conv1(MFMA) + relu + maxpool2. 512 thr = 8 waves; 1 img/wave,
// 2 rounds. Wave-local phases only (no block barriers after weight stage).
#define K1_WAVES 8
#define K1_ROUNDS 2
__global__ __launch_bounds__(512, 4) void k1_cor_conv1_pool(
    const float* __restrict__ x, const float* __restrict__ w1,
    const float* __restrict__ b1, _Float16* __restrict__ out1h)
{
    __shared__ float PAD[K1_WAVES][1444];        // 38x38 zero-padded ch (f32)
    __shared__ _Float16 COR[K1_WAVES][784];      // 28x28 cor output (f16)
    __shared__ _Float16 AW1[2 * 64 * 8];         // conv1 A-frags, 2 oc-tiles
    __shared__ float b1s[32];

    const int tid = threadIdx.x;
    const int wave = tid >> 6;
    const int lane = tid & 63;

    // ---- stage conv1 A-frags: A[oc][k=tap], taps 25..31 zeroed ----
    for (int e = tid; e < 1024; e += 512) {
        const int ln = (e >> 3) & 63;
        const int oc = ((e >> 9) << 4) + (ln & 15);
        const int k = ((ln >> 4) << 3) + (e & 7);
        AW1[e] = (k < 25) ? (_Float16)w1[oc * 25 + k] : (_Float16)0.f;
    }
    if (tid < 32) b1s[tid] = b1[tid];
    __syncthreads();

    const int g = lane >> 4;        // MFMA k-group / oc-subrow
    const int c = lane & 15;        // MFMA column
    int off[8];
#pragma unroll
    for (int jj = 0; jj < 8; ++jj) {
        const int k = g * 8 + jj;
        const int ky = k / 5;
        off[jj] = (k < 25) ? (ky * 28 + (k - ky * 5)) : 0;
    }
    const f16x8 af0 = *(const f16x8*)&AW1[lane * 8];
    const f16x8 af1 = *(const f16x8*)&AW1[(64 + lane) * 8];
    float bia0[4], bia1[4];
#pragma unroll
    for (int rr = 0; rr < 4; ++rr) {
        bia0[rr] = b1s[g * 4 + rr];
        bia1[rr] = b1s[16 + g * 4 + rr];
    }
    const int yy = lane >> 1;       // cor row (valid < 28)
    const int x0 = (lane & 1) * 14; // cor col base
    float* padw = &PAD[wave][0];
    _Float16* corw = &COR[wave][0];

    for (int r = 0; r < K1_ROUNDS; ++r) {
        const int img = blockIdx.x * (K1_WAVES * K1_ROUNDS) + r * K1_WAVES + wave;

        // ---- zero pad buffer, then fill interior with ch2 ----
        for (int i = lane; i < 361; i += 64)
            ((f32x4*)padw)[i] = (f32x4){0.f, 0.f, 0.f, 0.f};
        const float* xb = x + (size_t)img * B_STRIDE + 1568;  // channel 2
        for (int i = lane; i < 196; i += 64) {
            const float4 v = ((const float4*)xb)[i];
            const int yv = i / 7;
            float* d = &padw[(5 + yv) * 38 + 5 + (i - yv * 7) * 4];
            d[0] = v.x; d[1] = v.y; d[2] = v.z; d[3] = v.w;
        }

        // ---- cor: 56 lanes, one 14-wide half-row each; write f16 ----
        if (yy < 28) {
            float a[14];
#pragma unroll
            for (int t = 0; t < 14; ++t) a[t] = 0.f;
#pragma unroll
            for (int ky = 0; ky < 11; ++ky) {
                const float* prow = &padw[(yy + ky) * 38 + x0];
                float rr2[24];
#pragma unroll
                for (int t2 = 0; t2 < 12; ++t2) {
                    const float2 v2 = ((const float2*)prow)[t2];
                    rr2[2 * t2] = v2.x; rr2[2 * t2 + 1] = v2.y;
                }
                const float* trow = &padw[(13 + ky) * 38 + 13];
#pragma unroll
                for (int kx = 0; kx < 11; ++kx) {
                    const float w = trow[kx];   // broadcast
#pragma unroll
                    for (int t = 0; t < 14; ++t)
                        a[t] = fmaf(rr2[kx + t], w, a[t]);
                }
            }
            _Float16* cw = &corw[yy * 28 + x0];
#pragma unroll
            for (int t2 = 0; t2 < 7; ++t2) {
                f16x2 v2 = {(_Float16)a[2 * t2], (_Float16)a[2 * t2 + 1]};
                *(f16x2*)&cw[2 * t2] = v2;
            }
        }

        // ---- conv1 via MFMA: N ordered q-major so pool is in-lane ----
        _Float16* outw = out1h + (size_t)img * 4608;
#pragma unroll
        for (int jq = 0; jq < 9; ++jq) {
            const int pp = jq * 16 + c;
            const int py = pp / 12, px = pp - py * 12;
            f32x4 pm0, pm1;
#pragma unroll
            for (int q = 0; q < 4; ++q) {
                const int base = (2 * py + (q >> 1)) * 28 + 2 * px + (q & 1);
                f16x8 bf;
#pragma unroll
                for (int jj = 0; jj < 8; ++jj)
                    bf[jj] = corw[base + off[jj]];
                const f32x4 z = {0.f, 0.f, 0.f, 0.f};
                const f32x4 d0 = __builtin_amdgcn_mfma_f32_16x16x32_f16(af0, bf, z, 0, 0, 0);
                const f32x4 d1 = __builtin_amdgcn_mfma_f32_16x16x32_f16(af1, bf, z, 0, 0, 0);
                if (q == 0) { pm0 = d0; pm1 = d1; }
                else {
#pragma unroll
                    for (int rr = 0; rr < 4; ++rr) {
                        pm0[rr] = fmaxf(pm0[rr], d0[rr]);
                        pm1[rr] = fmaxf(pm1[rr], d1[rr]);
                    }
                }
            }
            f16x4 s0, s1;
#pragma unroll
            for (int rr = 0; rr < 4; ++rr) {
                s0[rr] = (_Float16)fmaxf(pm0[rr] + bia0[rr], 0.f);
                s1[rr] = (_Float16)fmaxf(pm1[rr] + bia1[rr], 0.f);
            }
            _Float16* dsth = outw + pp * 32 + g * 4;
            *(f16x4*)dsth = s0;
            *(f16x4*)(dsth + 16) = s1;
        }
    }
}

// ============================ Kernel 2 (MFMA fp16) =========================
// conv2 5x5 VALID (32->64) + relu + maxpool2. EXACT Round-3 structure:
// 512 thr = 8 waves; 2 waves share one image (each does 2 of 4 j-tiles),
// 4 img/round, 8 rounds, 2 block barriers per round. Proven: 90 us, ideal
// FETCH/WRITE traffic.
#define K2_ROUNDS 8
__global__ __launch_bounds__(512, 2) void k2_conv2_pool_mfma(
    const _Float16* __restrict__ in1h, const float* __restrict__ w2,
    const float* __restrict__ b2, float* __restrict__ out2)
{
    __shared__ __align__(16) _Float16 AW[25 * 4 * 64 * 8];   // 100 KB
    __shared__ __align__(16) _Float16 XT[4][4 * 144 * 8];    // 36 KB
    __shared__ float b2s[64];

    const int tid = threadIdx.x;
    const int wave = tid >> 6;
    const int lane = tid & 63;
    const int widx = wave >> 1;     // image slot 0..3
    const int half = wave & 1;      // j-tile half
    const int jb = half * 2;

    // ---- stage weights once per block ----
    for (int it = 0; it < 50; ++it) {
        const int flat = it * 512 + tid;             // (oc*16+icp)*25 + kpos
        const int rest = (flat * 5243) >> 17;        // flat / 25
        const int kpos = flat - rest * 25;
        const int oc = rest >> 4, icp = rest & 15;
        const float* gsrc = w2 + oc * 800 + icp * 50 + kpos;
        const f16x2 v = { (_Float16)gsrc[0], (_Float16)gsrc[25] };
        const int lane_w = (oc & 15) + (icp >> 2) * 16;
        const int idx = (((kpos * 4 + (oc >> 4)) * 64) + lane_w) * 8 + (icp & 3) * 2;
        *(f16x2*)&AW[idx] = v;
    }
    if (tid < 64) b2s[tid] = b2[tid];

    const int b0 = blockIdx.x * (4 * K2_ROUNDS);
    const int hi = (lane >> 3) & 1;
    const int ox = lane & 7;
    const int icg = lane >> 4;
    _Float16* xtw = &XT[widx][0];

    for (int r = 0; r < K2_ROUNDS; ++r) {
        __syncthreads();   // WAR on XT; first iter: AW visible
        const int img = b0 + r * 4 + widx;

        // ---- stage image (pair of waves): [pos][32ic] -> [icg][pos][8] ----
        const _Float16* srch = in1h + (size_t)img * 4608;
        for (int p = lane + half * 64; p < 144; p += 128) {
            const f16x8* s8 = (const f16x8*)(srch + p * 32);
#pragma unroll
            for (int ig = 0; ig < 4; ++ig)
                *(f16x8*)&xtw[(ig * 144 + p) * 8] = s8[ig];
        }
        __syncthreads();

        f32x4 acc[4][2];
#pragma unroll
        for (int i = 0; i < 4; ++i)
#pragma unroll
            for (int jj = 0; jj < 2; ++jj)
                acc[i][jj] = (f32x4){0.f, 0.f, 0.f, 0.f};

        const int prow = hi * 12 + ox;
#pragma unroll
        for (int kpos = 0; kpos < 25; ++kpos) {
            const int ky = kpos / 5, kx = kpos % 5;
            f16x8 af[4], bf[2];
#pragma unroll
            for (int i = 0; i < 4; ++i)
                af[i] = *(const f16x8*)&AW[(((kpos * 4 + i) * 64) + lane) * 8];
#pragma unroll
            for (int jj = 0; jj < 2; ++jj) {
                const int p = prow + (2 * (jb + jj) + ky) * 12 + kx;
                bf[jj] = *(const f16x8*)&xtw[(icg * 144 + p) * 8];
            }
#pragma unroll
            for (int i = 0; i < 4; ++i)
#pragma unroll
                for (int jj = 0; jj < 2; ++jj)
                    acc[i][jj] = __builtin_amdgcn_mfma_f32_16x16x32_f16(
                        af[i], bf[jj], acc[i][jj], 0, 0, 0);
        }

        // ---- epilogue: bias + relu + 2x2 pool + write [64][4][4] ----
        float* dst = out2 + (size_t)img * 1024;
#pragma unroll
        for (int i = 0; i < 4; ++i)
#pragma unroll
            for (int jj = 0; jj < 2; ++jj)
#pragma unroll
                for (int rr = 0; rr < 4; ++rr) {
                    const int oc = i * 16 + (lane >> 4) * 4 + rr;
                    float v = fmaxf(acc[i][jj][rr] + b2s[oc], 0.f);
                    v = fmaxf(v, __shfl_xor(v, 1));
                    v = fmaxf(v, __shfl_xor(v, 8));
                    if ((lane & 9) == 0)
                        dst[oc * 16 + (jb + jj) * 4 + (ox >> 1)] = v;
                }
    }
}

// ============================ Kernel 3 =====================================
// conv3 3x3 VALID (64->10) + relu + mean + log_softmax. 512 thr = 8 waves;
// wave owns 1 image/round, 4 rounds; weights staged once; all-lane mapping
// (icq 0..15 x pos 0..3), shuffle-tree reduce, in-lane softmax. No loop barriers.
#define K3_ROUNDS 4
__global__ __launch_bounds__(512, 4) void k3_conv3_head(
    const float* __restrict__ in2, const float* __restrict__ w3,
    const float* __restrict__ b3, float* __restrict__ out)
{
    __shared__ float w3s[5760];            // [oc][ic][3][3] flat
    __shared__ float b3s[16];
    __shared__ float xin[8][64 * 17];      // per-wave, 17-stride channels

    const int tid = threadIdx.x;
    const int wave = tid >> 6;
    const int lane = tid & 63;

    for (int i = tid; i < 5760; i += 512) w3s[i] = w3[i];
    if (tid < 10) b3s[tid] = b3[tid];
    __syncthreads();

    const int icq = lane >> 2;      // 0..15: ic quad
    const int pos = lane & 3;
    const int oy = pos >> 1, oxx = pos & 1;
    float* xw = &xin[wave][0];

    for (int r = 0; r < K3_ROUNDS; ++r) {
        const int img = blockIdx.x * (8 * K3_ROUNDS) + r * 8 + wave;

        // ---- wave-local stage: lane stages channel `lane` (stride 17) ----
        {
            const float4* s4 = (const float4*)(in2 + (size_t)img * 1024 + lane * 16);
            const float4 v0 = s4[0], v1 = s4[1], v2 = s4[2], v3 = s4[3];
            float* d = &xw[lane * 17];
            d[0] = v0.x;  d[1] = v0.y;  d[2] = v0.z;  d[3] = v0.w;
            d[4] = v1.x;  d[5] = v1.y;  d[6] = v1.z;  d[7] = v1.w;
            d[8] = v2.x;  d[9] = v2.y;  d[10] = v2.z; d[11] = v2.w;
            d[12] = v3.x; d[13] = v3.y; d[14] = v3.z; d[15] = v3.w;
        }

        // ---- conv3: lane accumulates 4 ics x 10 ocs over its 3x3 window ----
        float xv[4][9];
#pragma unroll
        for (int il = 0; il < 4; ++il) {
            const float* xc = &xw[(icq * 4 + il) * 17 + oy * 4 + oxx];
#pragma unroll
            for (int ky = 0; ky < 3; ++ky)
#pragma unroll
                for (int kx = 0; kx < 3; ++kx)
                    xv[il][ky * 3 + kx] = xc[ky * 4 + kx];
        }
        float acc[10];
#pragma unroll
        for (int oc = 0; oc < 10; ++oc) {
            float a = 0.f;
#pragma unroll
            for (int il = 0; il < 4; ++il) {
                const float* wc = &w3s[oc * 576 + (icq * 4 + il) * 9];
#pragma unroll
                for (int t = 0; t < 9; ++t)
                    a = fmaf(xv[il][t], wc[t], a);
            }
            acc[oc] = a;
        }

        // ---- reduce over icq (xor 4,8,16,32), bias+relu, mean over pos ----
        float lv[10];
#pragma unroll
        for (int oc = 0; oc < 10; ++oc) {
            float v = acc[oc];
            v += __shfl_xor(v, 4);
            v += __shfl_xor(v, 8);
            v += __shfl_xor(v, 16);
            v += __shfl_xor(v, 32);
            v = fmaxf(v + b3s[oc], 0.f);
            v += __shfl_xor(v, 1);
            v += __shfl_xor(v, 2);
            lv[oc] = v * 0.25f;
        }

        // ---- in-lane log_softmax; lane 0 writes ----
        float mx = lv[0];
#pragma unroll
        for (int oc = 1; oc < 10; ++oc) mx = fmaxf(mx, lv[oc]);
        float s = 0.f;
#pragma unroll
        for (int oc = 0; oc < 10; ++oc) s += expf(lv[oc] - mx);
        const float lse = mx + logf(s);
        if (lane == 0) {
            float* o = out + (size_t)img * 10;
#pragma unroll
            for (int oc = 0; oc < 10; ++oc) o[oc] = lv[oc] - lse;
        }
    }
}

// ============================ Launch =======================================
extern "C" void kernel_launch(void* const* d_in, const int* in_sizes, int n_in,
                              void* d_out, int out_size, void* d_ws, size_t ws_size,
                              hipStream_t stream)
{
    const float* x  = (const float*)d_in[0];
    const float* w1 = (const float*)d_in[1];
    const float* b1 = (const float*)d_in[2];
    const float* w2 = (const float*)d_in[3];
    const float* b2 = (const float*)d_in[4];
    const float* w3 = (const float*)d_in[5];
    const float* b3 = (const float*)d_in[6];
    float* out = (float*)d_out;

    const int B = in_sizes[0] / B_STRIDE;                         // 8192
    _Float16* pool1h = (_Float16*)d_ws;                           // B*4608 f16
    float* pool2 = (float*)((char*)d_ws + (size_t)B * 4608 * 2);  // B*1024 f32

    k1_cor_conv1_pool<<<B / (K1_WAVES * K1_ROUNDS), 512, 0, stream>>>(x, w1, b1, pool1h);
    k2_conv2_pool_mfma<<<B / (4 * K2_ROUNDS), 512, 0, stream>>>(pool1h, w2, b2, pool2);
    k3_conv3_head<<<B / (8 * K3_ROUNDS), 512, 0, stream>>>(pool2, w3, b3, out);
}

// Round 10
// 363.696 us; speedup vs baseline: 2.1266x; 1.0432x over previous
//
#include <hip/hip_runtime.h>
#include <hip/hip_bf16.h>
#include <math.h>

// ---------------------------------------------------------------------------
// Net: x(B,3,28,28) -> _cor (ch2 correlated with its 11x11 center) -> B,1,28,28
//      conv1 5x5 VALID (32) + relu + maxpool2 -> B,32,12,12   [MFMA fp16]
//      conv2 5x5 VALID (64) + relu + maxpool2 -> B,64,4,4     [MFMA fp16]
//      conv3 3x3 VALID (10) + relu + mean(hw) + log_softmax -> B,10
// pool1 stored fp16 in WAVE-NATIVE layout [img][jq 0..8][lane 0..63][8]:
//   lane = g*16+c, pos pp = jq*16+c, halves = oc {4g..4g+3, 16+4g..19+4g}.
//   k1 stores 1 KB contiguous per wave per instruction (fixes the 2.9x
//   partial-line write amplification measured in round 8); k2's LDS staging
//   performs the permutation.
// ---------------------------------------------------------------------------

#define B_STRIDE 2352   // 3*28*28

typedef _Float16 f16x8 __attribute__((ext_vector_type(8)));
typedef _Float16 f16x4 __attribute__((ext_vector_type(4)));
typedef _Float16 f16x2 __attribute__((ext_vector_type(2)));
typedef float f32x4 __attribute__((ext_vector_type(4)));

// ============================ Kernel 1 =====================================
// fused cor + conv1(MFMA) + relu + maxpool2. 512 thr = 8 waves; 1 img/wave,
// 2 rounds. Wave-local phases only (no block barriers after weight stage).
#define K1_WAVES 8
#define K1_ROUNDS 2
__global__ __launch_bounds__(512, 4) void k1_cor_conv1_pool(
    const float* __restrict__ x, const float* __restrict__ w1,
    const float* __restrict__ b1, _Float16* __restrict__ out1h)
{
    __shared__ float PAD[K1_WAVES][1444];        // 38x38 zero-padded ch (f32)
    __shared__ _Float16 COR[K1_WAVES][784];      // 28x28 cor output (f16)
    __shared__ _Float16 AW1[2 * 64 * 8];         // conv1 A-frags, 2 oc-tiles
    __shared__ float b1s[32];

    const int tid = threadIdx.x;
    const int wave = tid >> 6;
    const int lane = tid & 63;

    // ---- stage conv1 A-frags: A[oc][k=tap], taps 25..31 zeroed ----
    for (int e = tid; e < 1024; e += 512) {
        const int ln = (e >> 3) & 63;
        const int oc = ((e >> 9) << 4) + (ln & 15);
        const int k = ((ln >> 4) << 3) + (e & 7);
        AW1[e] = (k < 25) ? (_Float16)w1[oc * 25 + k] : (_Float16)0.f;
    }
    if (tid < 32) b1s[tid] = b1[tid];
    __syncthreads();

    const int g = lane >> 4;        // MFMA k-group / oc-subrow
    const int c = lane & 15;        // MFMA column
    int off[8];
#pragma unroll
    for (int jj = 0; jj < 8; ++jj) {
        const int k = g * 8 + jj;
        const int ky = k / 5;
        off[jj] = (k < 25) ? (ky * 28 + (k - ky * 5)) : 0;
    }
    const f16x8 af0 = *(const f16x8*)&AW1[lane * 8];
    const f16x8 af1 = *(const f16x8*)&AW1[(64 + lane) * 8];
    float bia0[4], bia1[4];
#pragma unroll
    for (int rr = 0; rr < 4; ++rr) {
        bia0[rr] = b1s[g * 4 + rr];
        bia1[rr] = b1s[16 + g * 4 + rr];
    }
    const int yy = lane >> 1;       // cor row (valid < 28)
    const int x0 = (lane & 1) * 14; // cor col base
    float* padw = &PAD[wave][0];
    _Float16* corw = &COR[wave][0];

    for (int r = 0; r < K1_ROUNDS; ++r) {
        const int img = blockIdx.x * (K1_WAVES * K1_ROUNDS) + r * K1_WAVES + wave;

        // ---- zero pad buffer, then fill interior with ch2 ----
        for (int i = lane; i < 361; i += 64)
            ((f32x4*)padw)[i] = (f32x4){0.f, 0.f, 0.f, 0.f};
        const float* xb = x + (size_t)img * B_STRIDE + 1568;  // channel 2
        for (int i = lane; i < 196; i += 64) {
            const float4 v = ((const float4*)xb)[i];
            const int yv = i / 7;
            float* d = &padw[(5 + yv) * 38 + 5 + (i - yv * 7) * 4];
            d[0] = v.x; d[1] = v.y; d[2] = v.z; d[3] = v.w;
        }

        // ---- cor: 56 lanes, one 14-wide half-row each; write f16 ----
        if (yy < 28) {
            float a[14];
#pragma unroll
            for (int t = 0; t < 14; ++t) a[t] = 0.f;
#pragma unroll
            for (int ky = 0; ky < 11; ++ky) {
                const float* prow = &padw[(yy + ky) * 38 + x0];
                float rr2[24];
#pragma unroll
                for (int t2 = 0; t2 < 12; ++t2) {
                    const float2 v2 = ((const float2*)prow)[t2];
                    rr2[2 * t2] = v2.x; rr2[2 * t2 + 1] = v2.y;
                }
                const float* trow = &padw[(13 + ky) * 38 + 13];
#pragma unroll
                for (int kx = 0; kx < 11; ++kx) {
                    const float w = trow[kx];   // broadcast
#pragma unroll
                    for (int t = 0; t < 14; ++t)
                        a[t] = fmaf(rr2[kx + t], w, a[t]);
                }
            }
            _Float16* cw = &corw[yy * 28 + x0];
#pragma unroll
            for (int t2 = 0; t2 < 7; ++t2) {
                f16x2 v2 = {(_Float16)a[2 * t2], (_Float16)a[2 * t2 + 1]};
                *(f16x2*)&cw[2 * t2] = v2;
            }
        }

        // ---- conv1 via MFMA: N ordered q-major so pool is in-lane ----
        // Output: wave-native layout, 1 f16x8 per lane per jq (contiguous 1KB).
        _Float16* outw = out1h + (size_t)img * 4608;
#pragma unroll
        for (int jq = 0; jq < 9; ++jq) {
            const int pp = jq * 16 + c;
            const int py = pp / 12, px = pp - py * 12;
            f32x4 pm0, pm1;
#pragma unroll
            for (int q = 0; q < 4; ++q) {
                const int base = (2 * py + (q >> 1)) * 28 + 2 * px + (q & 1);
                f16x8 bf;
#pragma unroll
                for (int jj = 0; jj < 8; ++jj)
                    bf[jj] = corw[base + off[jj]];
                const f32x4 z = {0.f, 0.f, 0.f, 0.f};
                const f32x4 d0 = __builtin_amdgcn_mfma_f32_16x16x32_f16(af0, bf, z, 0, 0, 0);
                const f32x4 d1 = __builtin_amdgcn_mfma_f32_16x16x32_f16(af1, bf, z, 0, 0, 0);
                if (q == 0) { pm0 = d0; pm1 = d1; }
                else {
#pragma unroll
                    for (int rr = 0; rr < 4; ++rr) {
                        pm0[rr] = fmaxf(pm0[rr], d0[rr]);
                        pm1[rr] = fmaxf(pm1[rr], d1[rr]);
                    }
                }
            }
            f16x8 s;
#pragma unroll
            for (int rr = 0; rr < 4; ++rr) {
                s[rr]     = (_Float16)fmaxf(pm0[rr] + bia0[rr], 0.f);  // oc g*4+rr
                s[4 + rr] = (_Float16)fmaxf(pm1[rr] + bia1[rr], 0.f);  // oc 16+g*4+rr
            }
            *(f16x8*)(outw + (jq * 64 + lane) * 8) = s;   // 1KB/wave/inst
        }
    }
}

// ============================ Kernel 2 (MFMA fp16) =========================
// conv2 5x5 VALID (32->64) + relu + maxpool2. Round-3 structure (proven):
// 512 thr = 8 waves; 2 waves share one image, 4 img/round, 8 rounds,
// 2 block barriers per round. Staging adapted to wave-native pool1 layout:
// contiguous f16x8 global reads, permuting split f16x4 LDS writes.
#define K2_ROUNDS 8
__global__ __launch_bounds__(512, 2) void k2_conv2_pool_mfma(
    const _Float16* __restrict__ in1h, const float* __restrict__ w2,
    const float* __restrict__ b2, float* __restrict__ out2)
{
    __shared__ __align__(16) _Float16 AW[25 * 4 * 64 * 8];   // 100 KB
    __shared__ __align__(16) _Float16 XT[4][4 * 144 * 8];    // 36 KB
    __shared__ float b2s[64];

    const int tid = threadIdx.x;
    const int wave = tid >> 6;
    const int lane = tid & 63;
    const int widx = wave >> 1;     // image slot 0..3
    const int half = wave & 1;      // j-tile half
    const int jb = half * 2;

    // ---- stage weights once per block ----
    for (int it = 0; it < 50; ++it) {
        const int flat = it * 512 + tid;             // (oc*16+icp)*25 + kpos
        const int rest = (flat * 5243) >> 17;        // flat / 25
        const int kpos = flat - rest * 25;
        const int oc = rest >> 4, icp = rest & 15;
        const float* gsrc = w2 + oc * 800 + icp * 50 + kpos;
        const f16x2 v = { (_Float16)gsrc[0], (_Float16)gsrc[25] };
        const int lane_w = (oc & 15) + (icp >> 2) * 16;
        const int idx = (((kpos * 4 + (oc >> 4)) * 64) + lane_w) * 8 + (icp & 3) * 2;
        *(f16x2*)&AW[idx] = v;
    }
    if (tid < 64) b2s[tid] = b2[tid];

    const int b0 = blockIdx.x * (4 * K2_ROUNDS);
    const int hi = (lane >> 3) & 1;
    const int ox = lane & 7;
    const int icg = lane >> 4;
    _Float16* xtw = &XT[widx][0];

    for (int r = 0; r < K2_ROUNDS; ++r) {
        __syncthreads();   // WAR on XT; first iter: AW visible
        const int img = b0 + r * 4 + widx;

        // ---- stage image (pair of waves): wave-native -> [icg][pos][8] ----
        // src bundle f = jq*64 + l (l = g*16+c): halves = oc {4g..4g+3,
        // 16+4g..19+4g} at pos pp = jq*16+c.
        const _Float16* srch = in1h + (size_t)img * 4608;
        for (int f = lane + half * 64; f < 576; f += 128) {
            const f16x8 v = *(const f16x8*)(srch + f * 8);
            const int l = f & 63, jq = f >> 6;
            const int gg = l >> 4, cc = l & 15;
            const int pp = jq * 16 + cc;
            const f16x4 lo = {v[0], v[1], v[2], v[3]};
            const f16x4 hi4 = {v[4], v[5], v[6], v[7]};
            *(f16x4*)&xtw[((gg >> 1) * 144 + pp) * 8 + (gg & 1) * 4] = lo;
            *(f16x4*)&xtw[(((gg >> 1) + 2) * 144 + pp) * 8 + (gg & 1) * 4] = hi4;
        }
        __syncthreads();

        f32x4 acc[4][2];
#pragma unroll
        for (int i = 0; i < 4; ++i)
#pragma unroll
            for (int jj = 0; jj < 2; ++jj)
                acc[i][jj] = (f32x4){0.f, 0.f, 0.f, 0.f};

        const int prow = hi * 12 + ox;
#pragma unroll
        for (int kpos = 0; kpos < 25; ++kpos) {
            const int ky = kpos / 5, kx = kpos % 5;
            f16x8 af[4], bf[2];
#pragma unroll
            for (int i = 0; i < 4; ++i)
                af[i] = *(const f16x8*)&AW[(((kpos * 4 + i) * 64) + lane) * 8];
#pragma unroll
            for (int jj = 0; jj < 2; ++jj) {
                const int p = prow + (2 * (jb + jj) + ky) * 12 + kx;
                bf[jj] = *(const f16x8*)&xtw[(icg * 144 + p) * 8];
            }
#pragma unroll
            for (int i = 0; i < 4; ++i)
#pragma unroll
                for (int jj = 0; jj < 2; ++jj)
                    acc[i][jj] = __builtin_amdgcn_mfma_f32_16x16x32_f16(
                        af[i], bf[jj], acc[i][jj], 0, 0, 0);
        }

        // ---- epilogue: bias + relu + 2x2 pool + write [64][4][4] ----
        float* dst = out2 + (size_t)img * 1024;
#pragma unroll
        for (int i = 0; i < 4; ++i)
#pragma unroll
            for (int jj = 0; jj < 2; ++jj)
#pragma unroll
                for (int rr = 0; rr < 4; ++rr) {
                    const int oc = i * 16 + (lane >> 4) * 4 + rr;
                    float v = fmaxf(acc[i][jj][rr] + b2s[oc], 0.f);
                    v = fmaxf(v, __shfl_xor(v, 1));
                    v = fmaxf(v, __shfl_xor(v, 8));
                    if ((lane & 9) == 0)
                        dst[oc * 16 + (jb + jj) * 4 + (ox >> 1)] = v;
                }
    }
}

// ============================ Kernel 3 =====================================
// conv3 3x3 VALID (64->10) + relu + mean + log_softmax. 512 thr = 8 waves;
// wave owns 1 image/round, 4 rounds; weights staged once; all-lane mapping
// (icq 0..15 x pos 0..3), shuffle-tree reduce, in-lane softmax. No loop barriers.
#define K3_ROUNDS 4
__global__ __launch_bounds__(512, 4) void k3_conv3_head(
    const float* __restrict__ in2, const float* __restrict__ w3,
    const float* __restrict__ b3, float* __restrict__ out)
{
    __shared__ float w3s[5760];            // [oc][ic][3][3] flat
    __shared__ float b3s[16];
    __shared__ float xin[8][64 * 17];      // per-wave, 17-stride channels

    const int tid = threadIdx.x;
    const int wave = tid >> 6;
    const int lane = tid & 63;

    for (int i = tid; i < 5760; i += 512) w3s[i] = w3[i];
    if (tid < 10) b3s[tid] = b3[tid];
    __syncthreads();

    const int icq = lane >> 2;      // 0..15: ic quad
    const int pos = lane & 3;
    const int oy = pos >> 1, oxx = pos & 1;
    float* xw = &xin[wave][0];

    for (int r = 0; r < K3_ROUNDS; ++r) {
        const int img = blockIdx.x * (8 * K3_ROUNDS) + r * 8 + wave;

        // ---- wave-local stage: lane stages channel `lane` (stride 17) ----
        {
            const float4* s4 = (const float4*)(in2 + (size_t)img * 1024 + lane * 16);
            const float4 v0 = s4[0], v1 = s4[1], v2 = s4[2], v3 = s4[3];
            float* d = &xw[lane * 17];
            d[0] = v0.x;  d[1] = v0.y;  d[2] = v0.z;  d[3] = v0.w;
            d[4] = v1.x;  d[5] = v1.y;  d[6] = v1.z;  d[7] = v1.w;
            d[8] = v2.x;  d[9] = v2.y;  d[10] = v2.z; d[11] = v2.w;
            d[12] = v3.x; d[13] = v3.y; d[14] = v3.z; d[15] = v3.w;
        }

        // ---- conv3: lane accumulates 4 ics x 10 ocs over its 3x3 window ----
        float xv[4][9];
#pragma unroll
        for (int il = 0; il < 4; ++il) {
            const float* xc = &xw[(icq * 4 + il) * 17 + oy * 4 + oxx];
#pragma unroll
            for (int ky = 0; ky < 3; ++ky)
#pragma unroll
                for (int kx = 0; kx < 3; ++kx)
                    xv[il][ky * 3 + kx] = xc[ky * 4 + kx];
        }
        float acc[10];
#pragma unroll
        for (int oc = 0; oc < 10; ++oc) {
            float a = 0.f;
#pragma unroll
            for (int il = 0; il < 4; ++il) {
                const float* wc = &w3s[oc * 576 + (icq * 4 + il) * 9];
#pragma unroll
                for (int t = 0; t < 9; ++t)
                    a = fmaf(xv[il][t], wc[t], a);
            }
            acc[oc] = a;
        }

        // ---- reduce over icq (xor 4,8,16,32), bias+relu, mean over pos ----
        float lv[10];
#pragma unroll
        for (int oc = 0; oc < 10; ++oc) {
            float v = acc[oc];
            v += __shfl_xor(v, 4);
            v += __shfl_xor(v, 8);
            v += __shfl_xor(v, 16);
            v += __shfl_xor(v, 32);
            v = fmaxf(v + b3s[oc], 0.f);
            v += __shfl_xor(v, 1);
            v += __shfl_xor(v, 2);
            lv[oc] = v * 0.25f;
        }

        // ---- in-lane log_softmax; lane 0 writes ----
        float mx = lv[0];
#pragma unroll
        for (int oc = 1; oc < 10; ++oc) mx = fmaxf(mx, lv[oc]);
        float s = 0.f;
#pragma unroll
        for (int oc = 0; oc < 10; ++oc) s += expf(lv[oc] - mx);
        const float lse = mx + logf(s);
        if (lane == 0) {
            float* o = out + (size_t)img * 10;
#pragma unroll
            for (int oc = 0; oc < 10; ++oc) o[oc] = lv[oc] - lse;
        }
    }
}

// ============================ Launch =======================================
extern "C" void kernel_launch(void* const* d_in, const int* in_sizes, int n_in,
                              void* d_out, int out_size, void* d_ws, size_t ws_size,
                              hipStream_t stream)
{
    const float* x  = (const float*)d_in[0];
    const float* w1 = (const float*)d_in[1];
    const float* b1 = (const float*)d_in[2];
    const float* w2 = (const float*)d_in[3];
    const float* b2 = (const float*)d_in[4];
    const float* w3 = (const float*)d_in[5];
    const float* b3 = (const float*)d_in[6];
    float* out = (float*)d_out;

    const int B = in_sizes[0] / B_STRIDE;                         // 8192
    _Float16* pool1h = (_Float16*)d_ws;                           // B*4608 f16
    float* pool2 = (float*)((char*)d_ws + (size_t)B * 4608 * 2);  // B*1024 f32

    k1_cor_conv1_pool<<<B / (K1_WAVES * K1_ROUNDS), 512, 0, stream>>>(x, w1, b1, pool1h);
    k2_conv2_pool_mfma<<<B / (4 * K2_ROUNDS), 512, 0, stream>>>(pool1h, w2, b2, pool2);
    k3_conv3_head<<<B / (8 * K3_ROUNDS), 512, 0, stream>>>(pool2, w3, b3, out);
}